// Round 11
// baseline (515.210 us; speedup 1.0000x reference)
//
#include <hip/hip_runtime.h>
#include <hip/hip_bf16.h>
#include <hip/hip_fp16.h>
#include <math.h>

#define N_NODES 100000
#define N_EDGES 1600000
#define SCAN_BLOCKS 98   // ceil(100000/1024)
#define XCD_RANGE 12500  // N_NODES / 8
#define CVT_BLOCKS 3125
#define CNT_BLOCKS 6250
#define ATT_BLOCKS 391

typedef _Float16 h8 __attribute__((ext_vector_type(8)));
typedef float f32x4 __attribute__((ext_vector_type(4)));

// ---------------- fused fp32->fp16 convert + target histogram ----------------
__global__ __launch_bounds__(256) void k_cvtcount(const float* __restrict__ feat,
                                                  _Float16* __restrict__ outH,
                                                  const int* __restrict__ tgt,
                                                  int* __restrict__ counts) {
    int b = blockIdx.x, t = threadIdx.x;
    if (b < CVT_BLOCKS) {
        int i = b * 256 + t;
        const f32x4* p = reinterpret_cast<const f32x4*>(feat) + (size_t)i * 2;
        f32x4 u = __builtin_nontemporal_load(p);
        f32x4 v = __builtin_nontemporal_load(p + 1);
        h8 o;
        o[0] = u[0]; o[1] = u[1]; o[2] = u[2]; o[3] = u[3];
        o[4] = v[0]; o[5] = v[1]; o[6] = v[2]; o[7] = v[3];
        *(reinterpret_cast<h8*>(outH) + i) = o;
    } else {
        int e = (b - CVT_BLOCKS) * 256 + t;
        atomicAdd(&counts[__builtin_nontemporal_load(tgt + e)], 1);
    }
}

// ------------- single-kernel exclusive scan (decoupled lookback) -----------
// 98 blocks (all co-resident on 256 CUs -> spin-wait is safe).
__global__ __launch_bounds__(256) void k_scan(const int* __restrict__ counts,
                                              int* __restrict__ rowptr,
                                              int* __restrict__ agg,
                                              int* __restrict__ flag) {
    int b = blockIdx.x, t = threadIdx.x;
    int base = b * 1024 + t * 4;
    int v0 = (base + 0 < N_NODES) ? counts[base + 0] : 0;
    int v1 = (base + 1 < N_NODES) ? counts[base + 1] : 0;
    int v2 = (base + 2 < N_NODES) ? counts[base + 2] : 0;
    int v3 = (base + 3 < N_NODES) ? counts[base + 3] : 0;
    int s = v0 + v1 + v2 + v3;
    __shared__ int sS[256];
    sS[t] = s;
    __syncthreads();
    for (int off = 1; off < 256; off <<= 1) {
        int add = (t >= off) ? sS[t - off] : 0;
        __syncthreads();
        sS[t] += add;
        __syncthreads();
    }
    int excl = sS[t] - s;
    if (t == 255) {
        agg[b] = sS[255];
        __threadfence();
        atomicExch(&flag[b], 1);
    }
    __shared__ int sOff;
    if (t == 0) {
        int off = 0;
        for (int p = b - 1; p >= 0; --p) {
            while (atomicAdd(&flag[p], 0) == 0) {}
            off += atomicAdd(&agg[p], 0);
        }
        sOff = off;
    }
    __syncthreads();
    int add = sOff;
    if (base + 0 < N_NODES) rowptr[base + 0] = excl + add;
    if (base + 1 < N_NODES) rowptr[base + 1] = excl + v0 + add;
    if (base + 2 < N_NODES) rowptr[base + 2] = excl + v0 + v1 + add;
    if (base + 3 < N_NODES) rowptr[base + 3] = excl + v0 + v1 + v2 + add;
}

// ---------------- CSR fill, XCD-partitioned, NT edge reads ----------------
// rowptr doubles as cursor: after this kernel rowptr[t] == end of row t.
__global__ __launch_bounds__(256) void k_fill(const int* __restrict__ ei,
                                              int* __restrict__ rowptr,
                                              int* __restrict__ csr) {
    int p = blockIdx.x & 7;
    int e = (blockIdx.x >> 3) * 256 + threadIdx.x;
    int t = __builtin_nontemporal_load(ei + N_EDGES + e);
    if ((unsigned)(t - p * XCD_RANGE) < XCD_RANGE) {
        int s = __builtin_nontemporal_load(ei + e);
        int pos = atomicAdd(&rowptr[t], 1);
        csr[pos] = s;
    }
}

// ---------------- fp16 row accumulate: 8 rows per wave-load ----------------
template <int LD>
__device__ __forceinline__ void gadd(float (&A)[8], const _Float16* __restrict__ x,
                                     int idx, int n, int cnt, int c8) {
    int s = __shfl(idx, n);
    h8 v = *reinterpret_cast<const h8*>(x + (size_t)s * LD + c8);
    float m = (n < cnt) ? 1.0f : 0.0f;
#pragma unroll
    for (int j = 0; j < 8; ++j) A[j] = fmaf((float)v[j], m, A[j]);
}

// ---------------- gather-mean D=64 (fp16 in/out, fp32 accum) --------------
__global__ __launch_bounds__(256) void k_gather64(const _Float16* __restrict__ x,
                                                  const int* __restrict__ rowptr,
                                                  const int* __restrict__ csr,
                                                  _Float16* __restrict__ agg) {
    int wid = (blockIdx.x * 256 + threadIdx.x) >> 6;  // node
    int lane = threadIdx.x & 63;
    if (wid >= N_NODES) return;
    int rs = (wid > 0) ? rowptr[wid - 1] : 0;
    int re = rowptr[wid];
    int sub = lane >> 3;
    int c8 = (lane & 7) * 8;
    float a0[8] = {0}, a1[8] = {0}, a2[8] = {0}, a3[8] = {0};
    for (int base = rs; base < re; base += 64) {
        int j = base + lane;
        int idx = (j < re) ? csr[j] : 0;
        int cnt = min(64, re - base);
        {
            gadd<64>(a0, x, idx, 0 + sub, cnt, c8);
            gadd<64>(a1, x, idx, 8 + sub, cnt, c8);
        }
        if (16 < cnt) {
            gadd<64>(a2, x, idx, 16 + sub, cnt, c8);
            gadd<64>(a3, x, idx, 24 + sub, cnt, c8);
        }
        if (32 < cnt) {
            gadd<64>(a0, x, idx, 32 + sub, cnt, c8);
            gadd<64>(a1, x, idx, 40 + sub, cnt, c8);
        }
        if (48 < cnt) {
            gadd<64>(a2, x, idx, 48 + sub, cnt, c8);
            gadd<64>(a3, x, idx, 56 + sub, cnt, c8);
        }
    }
    float acc[8];
#pragma unroll
    for (int j = 0; j < 8; ++j) acc[j] = (a0[j] + a1[j]) + (a2[j] + a3[j]);
#pragma unroll
    for (int m = 8; m <= 32; m <<= 1) {
#pragma unroll
        for (int j = 0; j < 8; ++j) acc[j] += __shfl_xor(acc[j], m);
    }
    if (lane < 8) {
        float invd = 1.0f / fmaxf((float)(re - rs), 1.0f);
        h8 o;
#pragma unroll
        for (int j = 0; j < 8; ++j) o[j] = (_Float16)(acc[j] * invd);
        *reinterpret_cast<h8*>(agg + (size_t)wid * 64 + c8) = o;
    }
}

// ------------- SAGE transform 64->64 via MFMA 16x16x32 f16 (layer 1) -------
template <bool RELU>
__global__ __launch_bounds__(256) void k_xform64m(const _Float16* __restrict__ x,
                                                  const _Float16* __restrict__ agg,
                                                  const float* __restrict__ Wl,
                                                  const float* __restrict__ b,
                                                  const float* __restrict__ Wr,
                                                  _Float16* __restrict__ out) {
    int lane = threadIdx.x & 63;
    int g = lane >> 4;   // k-group / row-group
    int r = lane & 15;   // A-row, C-col
    int wv = (blockIdx.x * 256 + threadIdx.x) >> 6;
    int nw = gridDim.x * 4;
    h8 wl[2][4], wr[2][4];
#pragma unroll
    for (int kt = 0; kt < 2; ++kt)
#pragma unroll
        for (int ct = 0; ct < 4; ++ct)
#pragma unroll
            for (int j = 0; j < 8; ++j) {
                int row = kt * 32 + g * 8 + j, col = ct * 16 + r;
                wl[kt][ct][j] = (_Float16)Wl[row * 64 + col];
                wr[kt][ct][j] = (_Float16)Wr[row * 64 + col];
            }
    float biasv[4];
#pragma unroll
    for (int ct = 0; ct < 4; ++ct) biasv[ct] = b[ct * 16 + r];
    for (int tile = wv; tile < N_NODES / 16; tile += nw) {
        int n0 = tile * 16;
        const h8* arow = reinterpret_cast<const h8*>(agg + (size_t)(n0 + r) * 64);
        const h8* xrow = reinterpret_cast<const h8*>(x + (size_t)(n0 + r) * 64);
        h8 aa0 = arow[g], aa1 = arow[4 + g];
        h8 ax0 = xrow[g], ax1 = xrow[4 + g];
        f32x4 acc[4];
#pragma unroll
        for (int ct = 0; ct < 4; ++ct) {
            acc[ct] = (f32x4){biasv[ct], biasv[ct], biasv[ct], biasv[ct]};
            acc[ct] = __builtin_amdgcn_mfma_f32_16x16x32_f16(aa0, wl[0][ct], acc[ct], 0, 0, 0);
            acc[ct] = __builtin_amdgcn_mfma_f32_16x16x32_f16(aa1, wl[1][ct], acc[ct], 0, 0, 0);
            acc[ct] = __builtin_amdgcn_mfma_f32_16x16x32_f16(ax0, wr[0][ct], acc[ct], 0, 0, 0);
            acc[ct] = __builtin_amdgcn_mfma_f32_16x16x32_f16(ax1, wr[1][ct], acc[ct], 0, 0, 0);
        }
#pragma unroll
        for (int reg = 0; reg < 4; ++reg) {
            float ss = acc[0][reg] * acc[0][reg] + acc[1][reg] * acc[1][reg] +
                       acc[2][reg] * acc[2][reg] + acc[3][reg] * acc[3][reg];
            ss += __shfl_xor(ss, 1);
            ss += __shfl_xor(ss, 2);
            ss += __shfl_xor(ss, 4);
            ss += __shfl_xor(ss, 8);
            float rinv = 1.0f / fmaxf(sqrtf(ss), 1e-12f);
            int row = n0 + g * 4 + reg;
#pragma unroll
            for (int ct = 0; ct < 4; ++ct) {
                float v = acc[ct][reg] * rinv;
                if (RELU) v = fmaxf(v, 0.0f);
                out[(size_t)row * 64 + ct * 16 + r] = (_Float16)v;
            }
        }
    }
}

// ------------- layer-2 transform fused with layer-3 pre-transforms ---------
__global__ __launch_bounds__(256) void k_xform64z(const _Float16* __restrict__ x,
                                                  const _Float16* __restrict__ agg,
                                                  const float* __restrict__ Wl,
                                                  const float* __restrict__ b,
                                                  const float* __restrict__ Wr,
                                                  const float* __restrict__ W3l,
                                                  const float* __restrict__ W3r,
                                                  _Float16* __restrict__ z,
                                                  _Float16* __restrict__ r3) {
    int lane = threadIdx.x & 63;
    int g = lane >> 4;
    int r = lane & 15;
    int wv4 = threadIdx.x >> 6;  // wave in block
    int wv = (blockIdx.x * 256 + threadIdx.x) >> 6;
    int nw = gridDim.x * 4;
    __shared__ _Float16 sT[4][16][72];
    h8 wl[2][4], wr[2][4];
#pragma unroll
    for (int kt = 0; kt < 2; ++kt)
#pragma unroll
        for (int ct = 0; ct < 4; ++ct)
#pragma unroll
            for (int j = 0; j < 8; ++j) {
                int row = kt * 32 + g * 8 + j, col = ct * 16 + r;
                wl[kt][ct][j] = (_Float16)Wl[row * 64 + col];
                wr[kt][ct][j] = (_Float16)Wr[row * 64 + col];
            }
    h8 wz[2][2], w3[2][2];
#pragma unroll
    for (int kt = 0; kt < 2; ++kt)
#pragma unroll
        for (int ct = 0; ct < 2; ++ct)
#pragma unroll
            for (int j = 0; j < 8; ++j) {
                int row = kt * 32 + g * 8 + j, col = ct * 16 + r;
                wz[kt][ct][j] = (_Float16)W3l[row * 32 + col];
                w3[kt][ct][j] = (_Float16)W3r[row * 32 + col];
            }
    float biasv[4];
#pragma unroll
    for (int ct = 0; ct < 4; ++ct) biasv[ct] = b[ct * 16 + r];
    for (int tile = wv; tile < N_NODES / 16; tile += nw) {
        int n0 = tile * 16;
        const h8* arow = reinterpret_cast<const h8*>(agg + (size_t)(n0 + r) * 64);
        const h8* xrow = reinterpret_cast<const h8*>(x + (size_t)(n0 + r) * 64);
        h8 aa0 = arow[g], aa1 = arow[4 + g];
        h8 ax0 = xrow[g], ax1 = xrow[4 + g];
        f32x4 acc[4];
#pragma unroll
        for (int ct = 0; ct < 4; ++ct) {
            acc[ct] = (f32x4){biasv[ct], biasv[ct], biasv[ct], biasv[ct]};
            acc[ct] = __builtin_amdgcn_mfma_f32_16x16x32_f16(aa0, wl[0][ct], acc[ct], 0, 0, 0);
            acc[ct] = __builtin_amdgcn_mfma_f32_16x16x32_f16(aa1, wl[1][ct], acc[ct], 0, 0, 0);
            acc[ct] = __builtin_amdgcn_mfma_f32_16x16x32_f16(ax0, wr[0][ct], acc[ct], 0, 0, 0);
            acc[ct] = __builtin_amdgcn_mfma_f32_16x16x32_f16(ax1, wr[1][ct], acc[ct], 0, 0, 0);
        }
        // normalize + relu -> h2 tile into LDS
#pragma unroll
        for (int reg = 0; reg < 4; ++reg) {
            float ss = acc[0][reg] * acc[0][reg] + acc[1][reg] * acc[1][reg] +
                       acc[2][reg] * acc[2][reg] + acc[3][reg] * acc[3][reg];
            ss += __shfl_xor(ss, 1);
            ss += __shfl_xor(ss, 2);
            ss += __shfl_xor(ss, 4);
            ss += __shfl_xor(ss, 8);
            float rinv = 1.0f / fmaxf(sqrtf(ss), 1e-12f);
            int row16 = g * 4 + reg;
#pragma unroll
            for (int ct = 0; ct < 4; ++ct) {
                float v = fmaxf(acc[ct][reg] * rinv, 0.0f);
                sT[wv4][row16][ct * 16 + r] = (_Float16)v;
            }
        }
        // re-fragment h2 as MFMA A-operand (same-wave LDS, no barrier needed)
        h8 ha0 = *reinterpret_cast<const h8*>(&sT[wv4][r][g * 8]);
        h8 ha1 = *reinterpret_cast<const h8*>(&sT[wv4][r][32 + g * 8]);
        f32x4 zacc[2], racc[2];
#pragma unroll
        for (int ct = 0; ct < 2; ++ct) {
            zacc[ct] = (f32x4){0, 0, 0, 0};
            zacc[ct] = __builtin_amdgcn_mfma_f32_16x16x32_f16(ha0, wz[0][ct], zacc[ct], 0, 0, 0);
            zacc[ct] = __builtin_amdgcn_mfma_f32_16x16x32_f16(ha1, wz[1][ct], zacc[ct], 0, 0, 0);
            racc[ct] = (f32x4){0, 0, 0, 0};
            racc[ct] = __builtin_amdgcn_mfma_f32_16x16x32_f16(ha0, w3[0][ct], racc[ct], 0, 0, 0);
            racc[ct] = __builtin_amdgcn_mfma_f32_16x16x32_f16(ha1, w3[1][ct], racc[ct], 0, 0, 0);
        }
#pragma unroll
        for (int reg = 0; reg < 4; ++reg) {
            int row = n0 + g * 4 + reg;
#pragma unroll
            for (int ct = 0; ct < 2; ++ct) {
                z[(size_t)row * 32 + ct * 16 + r] = (_Float16)zacc[ct][reg];
                r3[(size_t)row * 32 + ct * 16 + r] = (_Float16)racc[ct][reg];
            }
        }
    }
}

// ------------- gather-mean D=32 fused with layer-3 finalize ----------------
__global__ __launch_bounds__(256) void k_g32fin(const _Float16* __restrict__ z,
                                                const int* __restrict__ rowptr,
                                                const int* __restrict__ csr,
                                                const _Float16* __restrict__ r3,
                                                const float* __restrict__ b3,
                                                float* __restrict__ h3) {
    int wid = (blockIdx.x * 256 + threadIdx.x) >> 6;  // node
    int lane = threadIdx.x & 63;
    if (wid >= N_NODES) return;
    int sub = lane >> 2;
    int c8 = (lane & 3) * 8;
    float bb[8];
#pragma unroll
    for (int j = 0; j < 8; ++j) bb[j] = b3[c8 + j];
    int rs = (wid > 0) ? rowptr[wid - 1] : 0;
    int re = rowptr[wid];
    float a0[8] = {0}, a1[8] = {0}, a2[8] = {0}, a3[8] = {0};
    for (int base = rs; base < re; base += 64) {
        int j = base + lane;
        int idx = (j < re) ? csr[j] : 0;
        int cnt = min(64, re - base);
        gadd<32>(a0, z, idx, 0 + sub, cnt, c8);
        if (16 < cnt) gadd<32>(a1, z, idx, 16 + sub, cnt, c8);
        if (32 < cnt) gadd<32>(a2, z, idx, 32 + sub, cnt, c8);
        if (48 < cnt) gadd<32>(a3, z, idx, 48 + sub, cnt, c8);
    }
    float acc[8];
#pragma unroll
    for (int j = 0; j < 8; ++j) acc[j] = (a0[j] + a1[j]) + (a2[j] + a3[j]);
#pragma unroll
    for (int m = 4; m <= 32; m <<= 1) {
#pragma unroll
        for (int j = 0; j < 8; ++j) acc[j] += __shfl_xor(acc[j], m);
    }
    float invd = 1.0f / fmaxf((float)(re - rs), 1.0f);
    h8 rr = (lane < 4) ? *reinterpret_cast<const h8*>(r3 + (size_t)wid * 32 + c8)
                       : (h8){0, 0, 0, 0, 0, 0, 0, 0};
    float val[8];
    float ss = 0.f;
#pragma unroll
    for (int j = 0; j < 8; ++j) {
        val[j] = fmaf(acc[j], invd, (float)rr[j] + bb[j]);
        ss = fmaf(val[j], val[j], ss);
    }
    ss += __shfl_xor(ss, 1);
    ss += __shfl_xor(ss, 2);
    if (lane < 4) {
        float rinv = 1.0f / fmaxf(sqrtf(ss), 1e-12f);
        f32x4 o0 = {val[0] * rinv, val[1] * rinv, val[2] * rinv, val[3] * rinv};
        f32x4 o1 = {val[4] * rinv, val[5] * rinv, val[6] * rinv, val[7] * rinv};
        f32x4* op = reinterpret_cast<f32x4*>(h3 + (size_t)wid * 32 + c8);
        op[0] = o0;
        op[1] = o1;
    }
}

// ------------- column sum of h3 [N,32] -------------
__global__ __launch_bounds__(256) void k_colsum(const float* __restrict__ h,
                                                float* __restrict__ colsum) {
    int gid = blockIdx.x * 256 + threadIdx.x;
    const int total = N_NODES * 32;
    const int stride = 1024 * 256;
    float s = 0.0f;
    for (int i = gid; i < total; i += stride) s += h[i];
    s += __shfl_xor(s, 32);
    __shared__ float sP[4][32];
    int wave = threadIdx.x >> 6, lane = threadIdx.x & 63;
    if (lane < 32) sP[wave][lane] = s;
    __syncthreads();
    if (threadIdx.x < 32) {
        float v = sP[0][threadIdx.x] + sP[1][threadIdx.x] + sP[2][threadIdx.x] +
                  sP[3][threadIdx.x];
        atomicAdd(&colsum[threadIdx.x], v);
    }
}

// ------------- attention pool + fused head (last-block pattern) -----------
__global__ __launch_bounds__(256) void k_attpool(const float* __restrict__ h,
                                                 const float* __restrict__ colsum,
                                                 const float* __restrict__ Watt,
                                                 float* __restrict__ pooled,
                                                 int* __restrict__ done,
                                                 const float* __restrict__ Wfc,
                                                 const float* __restrict__ bfc,
                                                 const float* __restrict__ Ws,
                                                 const float* __restrict__ bs,
                                                 float* __restrict__ out) {
    __shared__ float sC[32];
    __shared__ float sP[4][32];
    int t = threadIdx.x;
    if (t < 32) {
        float acc = 0.0f;
#pragma unroll
        for (int f = 0; f < 32; ++f)
            acc += (colsum[f] * (1.0f / N_NODES)) * Watt[f * 32 + t];
        sC[t] = tanhf(acc);
    }
    __syncthreads();
    float p[32];
#pragma unroll
    for (int f = 0; f < 32; ++f) p[f] = 0.f;
    int stride = gridDim.x * 256;
    for (int n = blockIdx.x * 256 + t; n < N_NODES; n += stride) {
        const f32x4* row = reinterpret_cast<const f32x4*>(h + (size_t)n * 32);
        f32x4 r[8];
        float dot = 0.0f;
#pragma unroll
        for (int q = 0; q < 8; ++q) {
            r[q] = row[q];
            dot += r[q][0] * sC[q * 4] + r[q][1] * sC[q * 4 + 1] +
                   r[q][2] * sC[q * 4 + 2] + r[q][3] * sC[q * 4 + 3];
        }
        float att = 1.0f / (1.0f + expf(-dot));
#pragma unroll
        for (int q = 0; q < 8; ++q) {
            p[q * 4 + 0] = fmaf(att, r[q][0], p[q * 4 + 0]);
            p[q * 4 + 1] = fmaf(att, r[q][1], p[q * 4 + 1]);
            p[q * 4 + 2] = fmaf(att, r[q][2], p[q * 4 + 2]);
            p[q * 4 + 3] = fmaf(att, r[q][3], p[q * 4 + 3]);
        }
    }
#pragma unroll
    for (int f = 0; f < 32; ++f) {
#pragma unroll
        for (int m = 1; m < 64; m <<= 1) p[f] += __shfl_xor(p[f], m);
    }
    int wave = t >> 6, lane = t & 63;
    if (lane == 0) {
#pragma unroll
        for (int f = 0; f < 32; ++f) sP[wave][f] = p[f];
    }
    __syncthreads();
    if (t < 32) {
        float v = sP[0][t] + sP[1][t] + sP[2][t] + sP[3][t];
        atomicAdd(&pooled[t], v);
    }
    __threadfence();
    __shared__ int sLast;
    if (t == 0) sLast = atomicAdd(done, 1);
    __syncthreads();
    if (sLast == (int)gridDim.x - 1) {
        // all other blocks' pooled contributions are visible (ticket after fence)
        __shared__ float sPo[32];
        __shared__ float sH[16];
        if (t < 32) sPo[t] = atomicAdd(&pooled[t], 0.0f);
        __syncthreads();
        if (t < 16) {
            float acc = bfc[t];
#pragma unroll
            for (int f = 0; f < 32; ++f) acc += sPo[f] * Wfc[f * 16 + t];
            sH[t] = fmaxf(acc, 0.0f);
        }
        __syncthreads();
        if (t == 0) {
            float s = bs[0];
#pragma unroll
            for (int j = 0; j < 16; ++j) s += sH[j] * Ws[j];
            out[0] = 1.0f / (1.0f + expf(-s));
        }
    }
}

extern "C" void kernel_launch(void* const* d_in, const int* in_sizes, int n_in,
                              void* d_out, int out_size, void* d_ws, size_t ws_size,
                              hipStream_t stream) {
    const float* feat = (const float*)d_in[0];
    const int* ei = (const int*)d_in[1];
    const float* W1l = (const float*)d_in[2];
    const float* b1 = (const float*)d_in[3];
    const float* W1r = (const float*)d_in[4];
    const float* W2l = (const float*)d_in[5];
    const float* b2 = (const float*)d_in[6];
    const float* W2r = (const float*)d_in[7];
    const float* W3l = (const float*)d_in[8];
    const float* b3 = (const float*)d_in[9];
    const float* W3r = (const float*)d_in[10];
    const float* Watt = (const float*)d_in[11];
    const float* Wfc = (const float*)d_in[12];
    const float* bfc = (const float*)d_in[13];
    const float* Ws = (const float*)d_in[14];
    const float* bs = (const float*)d_in[15];
    float* out = (float*)d_out;

    // ---- workspace layout (ints) ----
    int* rowptr = (int*)d_ws;                 // 100000 (doubles as cursor)
    int* counts = rowptr + 100000;            // 100000
    float* colsum = (float*)(counts + 100000);  // 32
    float* pooled = colsum + 32;                // 32
    int* done = (int*)(pooled + 32);            // 1 (+3 pad)
    int* flag = done + 4;                       // 98
    int* agg = flag + 98;                       // 98 (+pad)
    int* csr = agg + 102;                       // 1,600,000
    _Float16* B1 = (_Float16*)(csr + N_EDGES);  // N*64 halves
    _Float16* B2 = B1 + (size_t)N_NODES * 64;
    _Float16* B3 = B2 + (size_t)N_NODES * 64;
    float* h3 = (float*)(B3 + (size_t)N_NODES * 64);  // N*32 fp32

    // ---- zero: counts, and the small control block {colsum..flag} ----
    hipMemsetAsync(counts, 0, N_NODES * sizeof(int), stream);
    hipMemsetAsync(colsum, 0, (32 + 32 + 4 + 98) * sizeof(int), stream);

    // ---- fused cvt + count; scan; fill ----
    k_cvtcount<<<CVT_BLOCKS + CNT_BLOCKS, 256, 0, stream>>>(feat, B1, ei + N_EDGES, counts);
    k_scan<<<SCAN_BLOCKS, 256, 0, stream>>>(counts, rowptr, agg, flag);
    k_fill<<<(N_EDGES / 256) * 8, 256, 0, stream>>>(ei, rowptr, csr);
    // after k_fill: rowptr[t] == end of row t

    // ---- layer 1: gather featH -> B2; xform(featH,B2) -> h1 = B3 ----
    k_gather64<<<25000, 256, 0, stream>>>(B1, rowptr, csr, B2);
    k_xform64m<true><<<512, 256, 0, stream>>>(B1, B2, W1l, b1, W1r, B3);

    // ---- layer 2 (+ fused layer-3 pretransforms) ----
    _Float16* z = B1;
    _Float16* r3 = B1 + (size_t)N_NODES * 32;
    k_gather64<<<25000, 256, 0, stream>>>(B3, rowptr, csr, B2);
    k_xform64z<<<512, 256, 0, stream>>>(B3, B2, W2l, b2, W2r, W3l, W3r, z, r3);

    // ---- layer 3: fused gather32 + finalize -> h3 (fp32) ----
    k_g32fin<<<25000, 256, 0, stream>>>(z, rowptr, csr, r3, b3, h3);

    // ---- pooling + fused head ----
    k_colsum<<<1024, 256, 0, stream>>>(h3, colsum);
    k_attpool<<<ATT_BLOCKS, 256, 0, stream>>>(h3, colsum, Watt, pooled, done,
                                              Wfc, bfc, Ws, bs, out);
}

// Round 13
// 493.945 us; speedup vs baseline: 1.0431x; 1.0431x over previous
//
#include <hip/hip_runtime.h>
#include <hip/hip_bf16.h>
#include <hip/hip_fp16.h>
#include <math.h>

#define N_NODES 100000
#define N_EDGES 1600000
#define SCAN_BLOCKS 98   // ceil(100000/1024)
#define XCD_RANGE 12500  // N_NODES / 8
#define CVT_BLOCKS 3125
#define CNT_BLOCKS 6250
#define ATT_BLOCKS 391

typedef _Float16 h8 __attribute__((ext_vector_type(8)));
typedef float f32x4 __attribute__((ext_vector_type(4)));

// ---------------- fused fp32->fp16 convert + target histogram ----------------
__global__ __launch_bounds__(256) void k_cvtcount(const float* __restrict__ feat,
                                                  _Float16* __restrict__ outH,
                                                  const int* __restrict__ tgt,
                                                  int* __restrict__ counts) {
    int b = blockIdx.x, t = threadIdx.x;
    if (b < CVT_BLOCKS) {
        int i = b * 256 + t;
        const f32x4* p = reinterpret_cast<const f32x4*>(feat) + (size_t)i * 2;
        f32x4 u = __builtin_nontemporal_load(p);
        f32x4 v = __builtin_nontemporal_load(p + 1);
        h8 o;
        o[0] = u[0]; o[1] = u[1]; o[2] = u[2]; o[3] = u[3];
        o[4] = v[0]; o[5] = v[1]; o[6] = v[2]; o[7] = v[3];
        *(reinterpret_cast<h8*>(outH) + i) = o;
    } else {
        int e = (b - CVT_BLOCKS) * 256 + t;
        atomicAdd(&counts[__builtin_nontemporal_load(tgt + e)], 1);
    }
}

// ------------- single-kernel exclusive scan (PARALLEL lookback) ------------
// 98 blocks, all co-resident on 256 CUs -> spin-wait is deadlock-free.
// Lane t < b polls predecessor t's flag; tree-reduce sums the aggregates.
__global__ __launch_bounds__(256) void k_scan(const int* __restrict__ counts,
                                              int* __restrict__ rowptr,
                                              int* __restrict__ aggr,
                                              int* __restrict__ flag) {
    int b = blockIdx.x, t = threadIdx.x;
    int base = b * 1024 + t * 4;
    int v0 = (base + 0 < N_NODES) ? counts[base + 0] : 0;
    int v1 = (base + 1 < N_NODES) ? counts[base + 1] : 0;
    int v2 = (base + 2 < N_NODES) ? counts[base + 2] : 0;
    int v3 = (base + 3 < N_NODES) ? counts[base + 3] : 0;
    int s = v0 + v1 + v2 + v3;
    __shared__ int sS[256];
    sS[t] = s;
    __syncthreads();
    for (int off = 1; off < 256; off <<= 1) {
        int add = (t >= off) ? sS[t - off] : 0;
        __syncthreads();
        sS[t] += add;
        __syncthreads();
    }
    int excl = sS[t] - s;
    if (t == 255) {
        aggr[b] = sS[255];
        __threadfence();
        atomicExch(&flag[b], 1);
    }
    // parallel lookback
    __shared__ int sPred[256];
    int pv = 0;
    if (t < b) {
        while (atomicAdd(&flag[t], 0) == 0) {}
        pv = atomicAdd(&aggr[t], 0);
    }
    sPred[t] = pv;
    __syncthreads();
    for (int off = 128; off; off >>= 1) {
        if (t < off) sPred[t] += sPred[t + off];
        __syncthreads();
    }
    int add = sPred[0];
    if (base + 0 < N_NODES) rowptr[base + 0] = excl + add;
    if (base + 1 < N_NODES) rowptr[base + 1] = excl + v0 + add;
    if (base + 2 < N_NODES) rowptr[base + 2] = excl + v0 + v1 + add;
    if (base + 3 < N_NODES) rowptr[base + 3] = excl + v0 + v1 + v2 + add;
}

// ---------------- CSR fill, XCD-partitioned, NT edge reads ----------------
// rowptr doubles as cursor: after this kernel rowptr[t] == end of row t.
__global__ __launch_bounds__(256) void k_fill(const int* __restrict__ ei,
                                              int* __restrict__ rowptr,
                                              int* __restrict__ csr) {
    int p = blockIdx.x & 7;
    int e = (blockIdx.x >> 3) * 256 + threadIdx.x;
    int t = __builtin_nontemporal_load(ei + N_EDGES + e);
    if ((unsigned)(t - p * XCD_RANGE) < XCD_RANGE) {
        int s = __builtin_nontemporal_load(ei + e);
        int pos = atomicAdd(&rowptr[t], 1);
        csr[pos] = s;
    }
}

// ---------------- fp16 row accumulate: 8 rows per wave-load ----------------
template <int LD>
__device__ __forceinline__ void gadd(float (&A)[8], const _Float16* __restrict__ x,
                                     int idx, int n, int cnt, int c8) {
    int s = __shfl(idx, n);
    h8 v = *reinterpret_cast<const h8*>(x + (size_t)s * LD + c8);
    float m = (n < cnt) ? 1.0f : 0.0f;
#pragma unroll
    for (int j = 0; j < 8; ++j) A[j] = fmaf((float)v[j], m, A[j]);
}

// ---------------- gather-mean D=64 (fp16 in/out, fp32 accum) --------------
__global__ __launch_bounds__(256) void k_gather64(const _Float16* __restrict__ x,
                                                  const int* __restrict__ rowptr,
                                                  const int* __restrict__ csr,
                                                  _Float16* __restrict__ agg) {
    int wid = (blockIdx.x * 256 + threadIdx.x) >> 6;  // node
    int lane = threadIdx.x & 63;
    if (wid >= N_NODES) return;
    int rs = (wid > 0) ? rowptr[wid - 1] : 0;
    int re = rowptr[wid];
    int sub = lane >> 3;
    int c8 = (lane & 7) * 8;
    float a0[8] = {0}, a1[8] = {0}, a2[8] = {0}, a3[8] = {0};
    for (int base = rs; base < re; base += 64) {
        int j = base + lane;
        int idx = (j < re) ? csr[j] : 0;
        int cnt = min(64, re - base);
        {
            gadd<64>(a0, x, idx, 0 + sub, cnt, c8);
            gadd<64>(a1, x, idx, 8 + sub, cnt, c8);
        }
        if (16 < cnt) {
            gadd<64>(a2, x, idx, 16 + sub, cnt, c8);
            gadd<64>(a3, x, idx, 24 + sub, cnt, c8);
        }
        if (32 < cnt) {
            gadd<64>(a0, x, idx, 32 + sub, cnt, c8);
            gadd<64>(a1, x, idx, 40 + sub, cnt, c8);
        }
        if (48 < cnt) {
            gadd<64>(a2, x, idx, 48 + sub, cnt, c8);
            gadd<64>(a3, x, idx, 56 + sub, cnt, c8);
        }
    }
    float acc[8];
#pragma unroll
    for (int j = 0; j < 8; ++j) acc[j] = (a0[j] + a1[j]) + (a2[j] + a3[j]);
#pragma unroll
    for (int m = 8; m <= 32; m <<= 1) {
#pragma unroll
        for (int j = 0; j < 8; ++j) acc[j] += __shfl_xor(acc[j], m);
    }
    if (lane < 8) {
        float invd = 1.0f / fmaxf((float)(re - rs), 1.0f);
        h8 o;
#pragma unroll
        for (int j = 0; j < 8; ++j) o[j] = (_Float16)(acc[j] * invd);
        *reinterpret_cast<h8*>(agg + (size_t)wid * 64 + c8) = o;
    }
}

// ------------- SAGE transform 64->64 via MFMA 16x16x32 f16 (layer 1) -------
template <bool RELU>
__global__ __launch_bounds__(256) void k_xform64m(const _Float16* __restrict__ x,
                                                  const _Float16* __restrict__ agg,
                                                  const float* __restrict__ Wl,
                                                  const float* __restrict__ b,
                                                  const float* __restrict__ Wr,
                                                  _Float16* __restrict__ out) {
    int lane = threadIdx.x & 63;
    int g = lane >> 4;   // k-group / row-group
    int r = lane & 15;   // A-row, C-col
    int wv = (blockIdx.x * 256 + threadIdx.x) >> 6;
    int nw = gridDim.x * 4;
    h8 wl[2][4], wr[2][4];
#pragma unroll
    for (int kt = 0; kt < 2; ++kt)
#pragma unroll
        for (int ct = 0; ct < 4; ++ct)
#pragma unroll
            for (int j = 0; j < 8; ++j) {
                int row = kt * 32 + g * 8 + j, col = ct * 16 + r;
                wl[kt][ct][j] = (_Float16)Wl[row * 64 + col];
                wr[kt][ct][j] = (_Float16)Wr[row * 64 + col];
            }
    float biasv[4];
#pragma unroll
    for (int ct = 0; ct < 4; ++ct) biasv[ct] = b[ct * 16 + r];
    for (int tile = wv; tile < N_NODES / 16; tile += nw) {
        int n0 = tile * 16;
        const h8* arow = reinterpret_cast<const h8*>(agg + (size_t)(n0 + r) * 64);
        const h8* xrow = reinterpret_cast<const h8*>(x + (size_t)(n0 + r) * 64);
        h8 aa0 = arow[g], aa1 = arow[4 + g];
        h8 ax0 = xrow[g], ax1 = xrow[4 + g];
        f32x4 acc[4];
#pragma unroll
        for (int ct = 0; ct < 4; ++ct) {
            acc[ct] = (f32x4){biasv[ct], biasv[ct], biasv[ct], biasv[ct]};
            acc[ct] = __builtin_amdgcn_mfma_f32_16x16x32_f16(aa0, wl[0][ct], acc[ct], 0, 0, 0);
            acc[ct] = __builtin_amdgcn_mfma_f32_16x16x32_f16(aa1, wl[1][ct], acc[ct], 0, 0, 0);
            acc[ct] = __builtin_amdgcn_mfma_f32_16x16x32_f16(ax0, wr[0][ct], acc[ct], 0, 0, 0);
            acc[ct] = __builtin_amdgcn_mfma_f32_16x16x32_f16(ax1, wr[1][ct], acc[ct], 0, 0, 0);
        }
#pragma unroll
        for (int reg = 0; reg < 4; ++reg) {
            float ss = acc[0][reg] * acc[0][reg] + acc[1][reg] * acc[1][reg] +
                       acc[2][reg] * acc[2][reg] + acc[3][reg] * acc[3][reg];
            ss += __shfl_xor(ss, 1);
            ss += __shfl_xor(ss, 2);
            ss += __shfl_xor(ss, 4);
            ss += __shfl_xor(ss, 8);
            float rinv = 1.0f / fmaxf(sqrtf(ss), 1e-12f);
            int row = n0 + g * 4 + reg;
#pragma unroll
            for (int ct = 0; ct < 4; ++ct) {
                float v = acc[ct][reg] * rinv;
                if (RELU) v = fmaxf(v, 0.0f);
                out[(size_t)row * 64 + ct * 16 + r] = (_Float16)v;
            }
        }
    }
}

// ------------- layer-2 transform fused with layer-3 pre-transforms ---------
__global__ __launch_bounds__(256) void k_xform64z(const _Float16* __restrict__ x,
                                                  const _Float16* __restrict__ agg,
                                                  const float* __restrict__ Wl,
                                                  const float* __restrict__ b,
                                                  const float* __restrict__ Wr,
                                                  const float* __restrict__ W3l,
                                                  const float* __restrict__ W3r,
                                                  _Float16* __restrict__ z,
                                                  _Float16* __restrict__ r3) {
    int lane = threadIdx.x & 63;
    int g = lane >> 4;
    int r = lane & 15;
    int wv4 = threadIdx.x >> 6;  // wave in block
    int wv = (blockIdx.x * 256 + threadIdx.x) >> 6;
    int nw = gridDim.x * 4;
    __shared__ _Float16 sT[4][16][72];
    h8 wl[2][4], wr[2][4];
#pragma unroll
    for (int kt = 0; kt < 2; ++kt)
#pragma unroll
        for (int ct = 0; ct < 4; ++ct)
#pragma unroll
            for (int j = 0; j < 8; ++j) {
                int row = kt * 32 + g * 8 + j, col = ct * 16 + r;
                wl[kt][ct][j] = (_Float16)Wl[row * 64 + col];
                wr[kt][ct][j] = (_Float16)Wr[row * 64 + col];
            }
    h8 wz[2][2], w3[2][2];
#pragma unroll
    for (int kt = 0; kt < 2; ++kt)
#pragma unroll
        for (int ct = 0; ct < 2; ++ct)
#pragma unroll
            for (int j = 0; j < 8; ++j) {
                int row = kt * 32 + g * 8 + j, col = ct * 16 + r;
                wz[kt][ct][j] = (_Float16)W3l[row * 32 + col];
                w3[kt][ct][j] = (_Float16)W3r[row * 32 + col];
            }
    float biasv[4];
#pragma unroll
    for (int ct = 0; ct < 4; ++ct) biasv[ct] = b[ct * 16 + r];
    for (int tile = wv; tile < N_NODES / 16; tile += nw) {
        int n0 = tile * 16;
        const h8* arow = reinterpret_cast<const h8*>(agg + (size_t)(n0 + r) * 64);
        const h8* xrow = reinterpret_cast<const h8*>(x + (size_t)(n0 + r) * 64);
        h8 aa0 = arow[g], aa1 = arow[4 + g];
        h8 ax0 = xrow[g], ax1 = xrow[4 + g];
        f32x4 acc[4];
#pragma unroll
        for (int ct = 0; ct < 4; ++ct) {
            acc[ct] = (f32x4){biasv[ct], biasv[ct], biasv[ct], biasv[ct]};
            acc[ct] = __builtin_amdgcn_mfma_f32_16x16x32_f16(aa0, wl[0][ct], acc[ct], 0, 0, 0);
            acc[ct] = __builtin_amdgcn_mfma_f32_16x16x32_f16(aa1, wl[1][ct], acc[ct], 0, 0, 0);
            acc[ct] = __builtin_amdgcn_mfma_f32_16x16x32_f16(ax0, wr[0][ct], acc[ct], 0, 0, 0);
            acc[ct] = __builtin_amdgcn_mfma_f32_16x16x32_f16(ax1, wr[1][ct], acc[ct], 0, 0, 0);
        }
        // normalize + relu -> h2 tile into LDS
#pragma unroll
        for (int reg = 0; reg < 4; ++reg) {
            float ss = acc[0][reg] * acc[0][reg] + acc[1][reg] * acc[1][reg] +
                       acc[2][reg] * acc[2][reg] + acc[3][reg] * acc[3][reg];
            ss += __shfl_xor(ss, 1);
            ss += __shfl_xor(ss, 2);
            ss += __shfl_xor(ss, 4);
            ss += __shfl_xor(ss, 8);
            float rinv = 1.0f / fmaxf(sqrtf(ss), 1e-12f);
            int row16 = g * 4 + reg;
#pragma unroll
            for (int ct = 0; ct < 4; ++ct) {
                float v = fmaxf(acc[ct][reg] * rinv, 0.0f);
                sT[wv4][row16][ct * 16 + r] = (_Float16)v;
            }
        }
        // re-fragment h2 as MFMA A-operand (same-wave LDS, no barrier needed)
        h8 ha0 = *reinterpret_cast<const h8*>(&sT[wv4][r][g * 8]);
        h8 ha1 = *reinterpret_cast<const h8*>(&sT[wv4][r][32 + g * 8]);
        f32x4 zacc[2], racc[2];
#pragma unroll
        for (int ct = 0; ct < 2; ++ct) {
            zacc[ct] = (f32x4){0, 0, 0, 0};
            zacc[ct] = __builtin_amdgcn_mfma_f32_16x16x32_f16(ha0, wz[0][ct], zacc[ct], 0, 0, 0);
            zacc[ct] = __builtin_amdgcn_mfma_f32_16x16x32_f16(ha1, wz[1][ct], zacc[ct], 0, 0, 0);
            racc[ct] = (f32x4){0, 0, 0, 0};
            racc[ct] = __builtin_amdgcn_mfma_f32_16x16x32_f16(ha0, w3[0][ct], racc[ct], 0, 0, 0);
            racc[ct] = __builtin_amdgcn_mfma_f32_16x16x32_f16(ha1, w3[1][ct], racc[ct], 0, 0, 0);
        }
#pragma unroll
        for (int reg = 0; reg < 4; ++reg) {
            int row = n0 + g * 4 + reg;
#pragma unroll
            for (int ct = 0; ct < 2; ++ct) {
                z[(size_t)row * 32 + ct * 16 + r] = (_Float16)zacc[ct][reg];
                r3[(size_t)row * 32 + ct * 16 + r] = (_Float16)racc[ct][reg];
            }
        }
    }
}

// ------------- gather-mean D=32 fused with layer-3 finalize ----------------
__global__ __launch_bounds__(256) void k_g32fin(const _Float16* __restrict__ z,
                                                const int* __restrict__ rowptr,
                                                const int* __restrict__ csr,
                                                const _Float16* __restrict__ r3,
                                                const float* __restrict__ b3,
                                                float* __restrict__ h3) {
    int wid = (blockIdx.x * 256 + threadIdx.x) >> 6;  // node
    int lane = threadIdx.x & 63;
    if (wid >= N_NODES) return;
    int sub = lane >> 2;
    int c8 = (lane & 3) * 8;
    float bb[8];
#pragma unroll
    for (int j = 0; j < 8; ++j) bb[j] = b3[c8 + j];
    int rs = (wid > 0) ? rowptr[wid - 1] : 0;
    int re = rowptr[wid];
    float a0[8] = {0}, a1[8] = {0}, a2[8] = {0}, a3[8] = {0};
    for (int base = rs; base < re; base += 64) {
        int j = base + lane;
        int idx = (j < re) ? csr[j] : 0;
        int cnt = min(64, re - base);
        gadd<32>(a0, z, idx, 0 + sub, cnt, c8);
        if (16 < cnt) gadd<32>(a1, z, idx, 16 + sub, cnt, c8);
        if (32 < cnt) gadd<32>(a2, z, idx, 32 + sub, cnt, c8);
        if (48 < cnt) gadd<32>(a3, z, idx, 48 + sub, cnt, c8);
    }
    float acc[8];
#pragma unroll
    for (int j = 0; j < 8; ++j) acc[j] = (a0[j] + a1[j]) + (a2[j] + a3[j]);
#pragma unroll
    for (int m = 4; m <= 32; m <<= 1) {
#pragma unroll
        for (int j = 0; j < 8; ++j) acc[j] += __shfl_xor(acc[j], m);
    }
    float invd = 1.0f / fmaxf((float)(re - rs), 1.0f);
    h8 rr = (lane < 4) ? *reinterpret_cast<const h8*>(r3 + (size_t)wid * 32 + c8)
                       : (h8){0, 0, 0, 0, 0, 0, 0, 0};
    float val[8];
    float ss = 0.f;
#pragma unroll
    for (int j = 0; j < 8; ++j) {
        val[j] = fmaf(acc[j], invd, (float)rr[j] + bb[j]);
        ss = fmaf(val[j], val[j], ss);
    }
    ss += __shfl_xor(ss, 1);
    ss += __shfl_xor(ss, 2);
    if (lane < 4) {
        float rinv = 1.0f / fmaxf(sqrtf(ss), 1e-12f);
        f32x4 o0 = {val[0] * rinv, val[1] * rinv, val[2] * rinv, val[3] * rinv};
        f32x4 o1 = {val[4] * rinv, val[5] * rinv, val[6] * rinv, val[7] * rinv};
        f32x4* op = reinterpret_cast<f32x4*>(h3 + (size_t)wid * 32 + c8);
        op[0] = o0;
        op[1] = o1;
    }
}

// ------------- column sum of h3 [N,32] -------------
__global__ __launch_bounds__(256) void k_colsum(const float* __restrict__ h,
                                                float* __restrict__ colsum) {
    int gid = blockIdx.x * 256 + threadIdx.x;
    const int total = N_NODES * 32;
    const int stride = 1024 * 256;
    float s = 0.0f;
    for (int i = gid; i < total; i += stride) s += h[i];
    s += __shfl_xor(s, 32);
    __shared__ float sP[4][32];
    int wave = threadIdx.x >> 6, lane = threadIdx.x & 63;
    if (lane < 32) sP[wave][lane] = s;
    __syncthreads();
    if (threadIdx.x < 32) {
        float v = sP[0][threadIdx.x] + sP[1][threadIdx.x] + sP[2][threadIdx.x] +
                  sP[3][threadIdx.x];
        atomicAdd(&colsum[threadIdx.x], v);
    }
}

// ------------- attention pool + fused head (last-block pattern) -----------
__global__ __launch_bounds__(256) void k_attpool(const float* __restrict__ h,
                                                 const float* __restrict__ colsum,
                                                 const float* __restrict__ Watt,
                                                 float* __restrict__ pooled,
                                                 int* __restrict__ done,
                                                 const float* __restrict__ Wfc,
                                                 const float* __restrict__ bfc,
                                                 const float* __restrict__ Ws,
                                                 const float* __restrict__ bs,
                                                 float* __restrict__ out) {
    __shared__ float sC[32];
    __shared__ float sP[4][32];
    int t = threadIdx.x;
    if (t < 32) {
        float acc = 0.0f;
#pragma unroll
        for (int f = 0; f < 32; ++f)
            acc += (colsum[f] * (1.0f / N_NODES)) * Watt[f * 32 + t];
        sC[t] = tanhf(acc);
    }
    __syncthreads();
    float p[32];
#pragma unroll
    for (int f = 0; f < 32; ++f) p[f] = 0.f;
    int stride = gridDim.x * 256;
    for (int n = blockIdx.x * 256 + t; n < N_NODES; n += stride) {
        const f32x4* row = reinterpret_cast<const f32x4*>(h + (size_t)n * 32);
        f32x4 r[8];
        float dot = 0.0f;
#pragma unroll
        for (int q = 0; q < 8; ++q) {
            r[q] = row[q];
            dot += r[q][0] * sC[q * 4] + r[q][1] * sC[q * 4 + 1] +
                   r[q][2] * sC[q * 4 + 2] + r[q][3] * sC[q * 4 + 3];
        }
        float att = 1.0f / (1.0f + expf(-dot));
#pragma unroll
        for (int q = 0; q < 8; ++q) {
            p[q * 4 + 0] = fmaf(att, r[q][0], p[q * 4 + 0]);
            p[q * 4 + 1] = fmaf(att, r[q][1], p[q * 4 + 1]);
            p[q * 4 + 2] = fmaf(att, r[q][2], p[q * 4 + 2]);
            p[q * 4 + 3] = fmaf(att, r[q][3], p[q * 4 + 3]);
        }
    }
#pragma unroll
    for (int f = 0; f < 32; ++f) {
#pragma unroll
        for (int m = 1; m < 64; m <<= 1) p[f] += __shfl_xor(p[f], m);
    }
    int wave = t >> 6, lane = t & 63;
    if (lane == 0) {
#pragma unroll
        for (int f = 0; f < 32; ++f) sP[wave][f] = p[f];
    }
    __syncthreads();
    if (t < 32) {
        float v = sP[0][t] + sP[1][t] + sP[2][t] + sP[3][t];
        atomicAdd(&pooled[t], v);
    }
    __threadfence();
    __shared__ int sLast;
    if (t == 0) sLast = atomicAdd(done, 1);
    __syncthreads();
    if (sLast == (int)gridDim.x - 1) {
        __shared__ float sPo[32];
        __shared__ float sH[16];
        if (t < 32) sPo[t] = atomicAdd(&pooled[t], 0.0f);
        __syncthreads();
        if (t < 16) {
            float acc = bfc[t];
#pragma unroll
            for (int f = 0; f < 32; ++f) acc += sPo[f] * Wfc[f * 16 + t];
            sH[t] = fmaxf(acc, 0.0f);
        }
        __syncthreads();
        if (t == 0) {
            float s = bs[0];
#pragma unroll
            for (int j = 0; j < 16; ++j) s += sH[j] * Ws[j];
            out[0] = 1.0f / (1.0f + expf(-s));
        }
    }
}

extern "C" void kernel_launch(void* const* d_in, const int* in_sizes, int n_in,
                              void* d_out, int out_size, void* d_ws, size_t ws_size,
                              hipStream_t stream) {
    const float* feat = (const float*)d_in[0];
    const int* ei = (const int*)d_in[1];
    const float* W1l = (const float*)d_in[2];
    const float* b1 = (const float*)d_in[3];
    const float* W1r = (const float*)d_in[4];
    const float* W2l = (const float*)d_in[5];
    const float* b2 = (const float*)d_in[6];
    const float* W2r = (const float*)d_in[7];
    const float* W3l = (const float*)d_in[8];
    const float* b3 = (const float*)d_in[9];
    const float* W3r = (const float*)d_in[10];
    const float* Watt = (const float*)d_in[11];
    const float* Wfc = (const float*)d_in[12];
    const float* bfc = (const float*)d_in[13];
    const float* Ws = (const float*)d_in[14];
    const float* bs = (const float*)d_in[15];
    float* out = (float*)d_out;

    // ---- workspace layout (ints) ----
    int* rowptr = (int*)d_ws;                 // 100000 (doubles as cursor)
    int* counts = rowptr + 100000;            // 100000
    float* colsum = (float*)(counts + 100000);  // 32
    float* pooled = colsum + 32;                // 32
    int* done = (int*)(pooled + 32);            // 1 (+3 pad)
    int* flag = done + 4;                       // 98
    int* aggr = flag + 98;                      // 98 (+pad)
    int* csr = aggr + 102;                      // 1,600,000
    _Float16* B1 = (_Float16*)(csr + N_EDGES);  // N*64 halves
    _Float16* B2 = B1 + (size_t)N_NODES * 64;
    _Float16* B3 = B2 + (size_t)N_NODES * 64;
    float* h3 = (float*)(B3 + (size_t)N_NODES * 64);  // N*32 fp32

    // ---- zero: counts, and the small control block {colsum..aggr} ----
    hipMemsetAsync(counts, 0, N_NODES * sizeof(int), stream);
    hipMemsetAsync(colsum, 0, (32 + 32 + 4 + 98 + 102) * sizeof(int), stream);

    // ---- fused cvt + count; scan; fill ----
    k_cvtcount<<<CVT_BLOCKS + CNT_BLOCKS, 256, 0, stream>>>(feat, B1, ei + N_EDGES, counts);
    k_scan<<<SCAN_BLOCKS, 256, 0, stream>>>(counts, rowptr, aggr, flag);
    k_fill<<<(N_EDGES / 256) * 8, 256, 0, stream>>>(ei, rowptr, csr);
    // after k_fill: rowptr[t] == end of row t

    // ---- layer 1: gather featH -> B2; xform(featH,B2) -> h1 = B3 ----
    k_gather64<<<25000, 256, 0, stream>>>(B1, rowptr, csr, B2);
    k_xform64m<true><<<512, 256, 0, stream>>>(B1, B2, W1l, b1, W1r, B3);

    // ---- layer 2 (+ fused layer-3 pretransforms) ----
    _Float16* z = B1;
    _Float16* r3 = B1 + (size_t)N_NODES * 32;
    k_gather64<<<25000, 256, 0, stream>>>(B3, rowptr, csr, B2);
    k_xform64z<<<512, 256, 0, stream>>>(B3, B2, W2l, b2, W2r, W3l, W3r, z, r3);

    // ---- layer 3: fused gather32 + finalize -> h3 (fp32) ----
    k_g32fin<<<25000, 256, 0, stream>>>(z, rowptr, csr, r3, b3, h3);

    // ---- pooling + fused head ----
    k_colsum<<<1024, 256, 0, stream>>>(h3, colsum);
    k_attpool<<<ATT_BLOCKS, 256, 0, stream>>>(h3, colsum, Watt, pooled, done,
                                              Wfc, bfc, Ws, bs, out);
}